// Round 20
// baseline (88.107 us; speedup 1.0000x reference)
//
#include <hip/hip_runtime.h>
#include <math.h>

typedef short bf16x8 __attribute__((ext_vector_type(8)));
typedef _Float16 f16x8 __attribute__((ext_vector_type(8)));
typedef _Float16 f16x4 __attribute__((ext_vector_type(4)));
typedef float f32x4 __attribute__((ext_vector_type(4)));
typedef unsigned short u16x4 __attribute__((ext_vector_type(4)));

#define S_LEN 2048
#define E_DIM 1024
#define H_NUM 16
#define D_DIM 64
#define LDP   (3 * E_DIM)
// softmax scale folded into Q at GEMM1 epilogue: 1/sqrt(64) * log2(e)
#define QSCALE 0.18033688011112042f

#define MFMA16(a, b, c)  __builtin_amdgcn_mfma_f32_16x16x32_bf16((a), (b), (c), 0, 0, 0)
#define MFMA16H(a, b, c) __builtin_amdgcn_mfma_f32_16x16x32_f16((a), (b), (c), 0, 0, 0)

__device__ __forceinline__ unsigned short f2bf(float f) {
    union { float f; unsigned int u; } v; v.f = f;
    unsigned int r = v.u + 0x7FFFu + ((v.u >> 16) & 1u);
    return (unsigned short)(r >> 16);
}
__device__ __forceinline__ float exp2_fast(float x) {
    float r; asm("v_exp_f32 %0, %1" : "=v"(r) : "v"(x)); return r;
}
__device__ __forceinline__ unsigned int cvt_pk_bf16(float lo, float hi) {
    unsigned int r;
    asm("v_cvt_pk_bf16_f32 %0, %1, %2" : "=v"(r) : "v"(lo), "v"(hi));
    return r;
}
// direct global -> LDS, 16B per lane. LDS dest = wave-uniform base + lane*16.
__device__ __forceinline__ void gl_lds16(const void* g, unsigned short* l) {
    __builtin_amdgcn_global_load_lds(
        (const __attribute__((address_space(1))) void*)g,
        (__attribute__((address_space(3))) void*)l, 16, 0, 0);
}

// ---------------------------------------------------------------------------
// Fused prep: [0,2048) convert qkv fp32 -> f16; [2048,2816) transpose w_in;
// [2816,3072) transpose w_out.
// ---------------------------------------------------------------------------
__global__ __launch_bounds__(256) void prep_kernel(
    const float* __restrict__ qkv, _Float16* __restrict__ Ah,
    const float* __restrict__ w_in, _Float16* __restrict__ Wt1,
    const float* __restrict__ w_out, _Float16* __restrict__ Wt2)
{
    __shared__ float tile[64][65];
    const int bid = blockIdx.x;
    const int t = threadIdx.x;

    if (bid < 2048) {
        const int i = bid * 256 + t;
        const float4 v = ((const float4*)qkv)[i];
        f16x4 hh;
        hh[0] = (_Float16)v.x; hh[1] = (_Float16)v.y;
        hh[2] = (_Float16)v.z; hh[3] = (_Float16)v.w;
        ((f16x4*)Ah)[i] = hh;
        return;
    }
    const float* B;
    _Float16* Bt;
    int bx, by, N;
    if (bid < 2816) { B = w_in;  Bt = Wt1; N = 3 * E_DIM; bx = (bid - 2048) % 48; by = (bid - 2048) / 48; }
    else            { B = w_out; Bt = Wt2; N = E_DIM;     bx = (bid - 2816) % 16; by = (bid - 2816) / 16; }
    const int K = E_DIM;
    const int k0 = by * 64, n0 = bx * 64;
    const int r4 = t >> 6, c = t & 63;
#pragma unroll
    for (int rep = 0; rep < 16; ++rep)
        tile[rep * 4 + r4][c] = B[(size_t)(k0 + rep * 4 + r4) * N + n0 + c];
    __syncthreads();
#pragma unroll
    for (int rep = 0; rep < 16; ++rep) {
        const int n = rep * 4 + r4;
        Bt[(size_t)(n0 + n) * K + k0 + c] = (_Float16)tile[c][n];
    }
}

// ---------------------------------------------------------------------------
// f16 MFMA GEMM, global_load_lds staging + LDS double buffer (r10-proven).
// ---------------------------------------------------------------------------
template <int BM, int BN, int OUT_MODE, int TWO_PASS>
__global__ __launch_bounds__(256) void gemm_f16_kernel(
    const _Float16* __restrict__ Ah, const _Float16* __restrict__ Al,
    const _Float16* __restrict__ Bt, const float* __restrict__ bias,
    void* __restrict__ Cout, int M, int N, int K, int nbx)
{
    constexpr int AROWS = TWO_PASS ? 2 * BM : BM;
    constexpr int ROWS = AROWS + BN;
    constexpr int NISS = ROWS / 16;
    constexpr int MI = BM / 32, NI = BN / 32;
    __shared__ unsigned short lds[2 * ROWS * 32];

    const int nwg = gridDim.x;
    const int bid = blockIdx.x;
    const int qch = nwg >> 3;
    const int swz = (bid & 7) * qch + (bid >> 3);
    const int n0 = (swz % nbx) * BN;
    const int m0 = (swz / nbx) * BM;

    const int t = threadIdx.x;
    const int wid = t >> 6, lane = t & 63;
    const int wr = wid >> 1, wc = wid & 1;
    const int lc = lane & 15, g = lane >> 4;
    const int lrow = lane >> 2;
    const int lcol = (lane & 3) * 8;

    f32x4 acc[MI][NI];
    const f32x4 zf = {0.f, 0.f, 0.f, 0.f};
#pragma unroll
    for (int mi = 0; mi < MI; ++mi)
#pragma unroll
        for (int ni = 0; ni < NI; ++ni) acc[mi][ni] = zf;

    auto stage = [&](int k0, int b) {
        unsigned short* base = &lds[b * ROWS * 32];
#pragma unroll
        for (int e = wid; e < NISS; e += 4) {
            const int rb = e * 16;
            const int rr = rb + lrow;
            const _Float16* gp;
            if (rb < BM)                            gp = &Ah[(size_t)(m0 + rr) * K + k0 + lcol];
            else if (TWO_PASS && rb < 2 * BM)       gp = &Al[(size_t)(m0 + rr - BM) * K + k0 + lcol];
            else                                    gp = &Bt[(size_t)(n0 + rr - AROWS) * K + k0 + lcol];
            gl_lds16(gp, base + rb * 32);
        }
    };

    stage(0, 0);
    const int NK = K / 32;
    for (int ks = 0; ks < NK; ++ks) {
        __syncthreads();
        if (ks + 1 < NK) stage((ks + 1) * 32, (ks + 1) & 1);
        const unsigned short* cb = &lds[(ks & 1) * ROWS * 32];

        f16x8 bfr[NI];
#pragma unroll
        for (int ni = 0; ni < NI; ++ni)
            bfr[ni] = *(const f16x8*)&cb[(AROWS + wc * (BN / 2) + ni * 16 + lc) * 32 + g * 8];
#pragma unroll
        for (int mi = 0; mi < MI; ++mi) {
            const int ar = wr * (BM / 2) + mi * 16 + lc;
            const f16x8 ah = *(const f16x8*)&cb[ar * 32 + g * 8];
#pragma unroll
            for (int ni = 0; ni < NI; ++ni)
                acc[mi][ni] = MFMA16H(ah, bfr[ni], acc[mi][ni]);
            if (TWO_PASS) {
                const f16x8 al = *(const f16x8*)&cb[(BM + ar) * 32 + g * 8];
#pragma unroll
                for (int ni = 0; ni < NI; ++ni)
                    acc[mi][ni] = MFMA16H(al, bfr[ni], acc[mi][ni]);
            }
        }
    }

#pragma unroll
    for (int ni = 0; ni < NI; ++ni) {
        const int col = n0 + wc * (BN / 2) + ni * 16 + lc;
        const float bv = bias[col];
        float sc = 1.f;
        if (OUT_MODE == 1) sc = (col < E_DIM) ? QSCALE : 1.f;
#pragma unroll
        for (int mi = 0; mi < MI; ++mi) {
            const int rbase = m0 + wr * (BM / 2) + mi * 16 + g * 4;
#pragma unroll
            for (int i = 0; i < 4; ++i) {
                const float v = acc[mi][ni][i] + bv;
                if (OUT_MODE == 1)
                    ((unsigned short*)Cout)[(size_t)(rbase + i) * N + col] = f2bf(v * sc);
                else
                    ((float*)Cout)[(size_t)(rbase + i) * N + col] = v;
            }
        }
    }
}

// ---------------------------------------------------------------------------
// MFMA flash attention (r10 structure): K via global_load_lds DMA double
// buffer (r19-proven), V via reg-transpose into a DOUBLE buffer -> ONE
// barrier per tile. V[buf^1]'s last readers were barrier-separated at tile
// tt-1, so storing it after PV is race-free. Barriers: 33 -> 18 per block.
// Block = 64 Q rows x head, 8 waves: waves 0-3 kv[0,1024), 4-7 kv[1024,2048).
// LDS: K 2x2x8KB | V 2x2x8KB | Q/P 8KB = 72KB -> 2 blocks/CU (grid-limited).
// ---------------------------------------------------------------------------
__global__ __launch_bounds__(512, 4) void attn_mfma_kernel(
    const unsigned short* __restrict__ proj, _Float16* __restrict__ Oh)
{
    // elems: K [2 half][2 buf][64][64] @0 | Vt [2 half][2 buf][64][64] @16384
    //        Q/P @32768
    __shared__ unsigned short lds[36864];   // 72 KB
    float* ldsf = (float*)lds;              // merge scratch overlays dead K
    const int QP = 32768;

    const int t = threadIdx.x;
    const int w = t >> 6, lane = t & 63;
    const int lc = lane & 15, g = lane >> 4;
    const int qg = w & 3;        // q-row group (16 rows)
    const int half = w >> 2;     // kv half
    const int ts = t & 255;

    const int bid = blockIdx.x;
    const int swb = (bid & 7) * 64 + (bid >> 3);
    const int qt = swb & 31;
    const int h  = swb >> 5;
    const int q0 = qt * 64;

    const size_t qoff = (size_t)h * D_DIM;
    const size_t koff = E_DIM + (size_t)h * D_DIM;
    const size_t voff = 2 * E_DIM + (size_t)h * D_DIM;

    const int KH = half * 8192;            // K base for this half (2 bufs)
    const int VH = 16384 + half * 8192;    // V base for this half (2 bufs)
    const int kvbase = half * (S_LEN / 2);

    // V staging coords (within 256-thread half-group)
    const int r  = ts >> 2;           // 0..63 (also used for Q staging)
    const int s  = (ts & 3) * 16;
    const int sw = (r & 7) << 3;
    const int kv = (ts & 15) * 4;     // V-transpose src rows
    const int d0 = (ts >> 4) * 4;     // V-transpose dst rows

    u16x4 vr[4];
    auto load_v = [&](int tile) {
        const int t0 = kvbase + tile * 64;
#pragma unroll
        for (int r2 = 0; r2 < 4; ++r2)
            vr[r2] = *(const u16x4*)&proj[(size_t)(t0 + kv + r2) * LDP + voff + d0];
    };
    auto store_v = [&](int buf) {
        unsigned short* vb = &lds[VH + buf * 4096];
#pragma unroll
        for (int j = 0; j < 4; ++j) {
            u16x4 w4; w4[0] = vr[0][j]; w4[1] = vr[1][j]; w4[2] = vr[2][j]; w4[3] = vr[3][j];
            const int d = d0 + j;
            *(u16x4*)&vb[d * 64 + (kv ^ ((d & 7) << 3))] = w4;
        }
    };

    // K staging: gl_lds DMA, pre-swizzled source, linear dest (r19-proven).
    const int klr = lane >> 3, ksl = lane & 7;
    const int ksrc = (ksl ^ klr) * 8;
    const int wh = w & 3;               // wave index within half
    auto stage_k = [&](int tile, int buf) {
        const int t0 = kvbase + tile * 64;
        unsigned short* kb = &lds[KH + buf * 4096];
#pragma unroll
        for (int e = 0; e < 2; ++e) {
            const int rb = (wh * 2 + e) * 8;
            gl_lds16(&proj[(size_t)(t0 + rb + klr) * LDP + koff + ksrc],
                     kb + rb * 64);
        }
    };

    // --- prologue: K tile 0 via DMA, V tile 0 via regs, Q staged (group 0) ---
    stage_k(0, 0);
    if (half == 0) {
        const unsigned short* gq = &proj[(size_t)(q0 + r) * LDP + qoff + s];
        const uint4 v0 = ((const uint4*)gq)[0];
        const uint4 v1 = ((const uint4*)gq)[1];
        *(uint4*)&lds[QP + r * 64 + (s ^ sw)]       = v0;
        *(uint4*)&lds[QP + r * 64 + ((s + 8) ^ sw)] = v1;
    }
    load_v(0);
    store_v(0);
    __syncthreads();   // drains K DMA (vmcnt) + Q/V ds_writes

    // hoist Q fragments: lane owns q-row qg*16+lc
    bf16x8 qB0, qB1;
    {
        const int rq = qg * 16 + lc;
        const int swq = (rq & 7) << 3;
        qB0 = *(const bf16x8*)&lds[QP + rq * 64 + ((g * 8) ^ swq)];
        qB1 = *(const bf16x8*)&lds[QP + rq * 64 + ((32 + g * 8) ^ swq)];
    }
    __syncthreads();   // all waves hoisted Q before P overlays the region

    f32x4 oacc[4];
    const f32x4 zf = {0.f, 0.f, 0.f, 0.f};
#pragma unroll
    for (int i = 0; i < 4; ++i) oacc[i] = zf;
    float mrun = -1e30f;   // defer-max high-water mark (T13)
    float lsum = 0.f;      // per-lane partial sum (reduced after loop)

    // per-wave P chunk: 16 rows x 32 kv-cols, overlaid on Q region.
    const int pb = QP + w * 512 + lc * 32;
    const int psw = ((lc >> 1) & 3) << 3;

    const int NTH = (S_LEN / 2) / 64;   // 16 tiles per half
    for (int tt = 0; tt < NTH; ++tt) {
        // issue next tile early: K DMA into other buffer; V into regs (T14)
        if (tt + 1 < NTH) {
            stage_k(tt + 1, (tt + 1) & 1);
            load_v(tt + 1);
        }
        const int KO = KH + (tt & 1) * 4096;
        const int VO = VH + (tt & 1) * 4096;

        // --- QK^T (swapped: A=K, B=Q): sacc[c][i] = S[kv=c*16+4g+i][q=lc] ---
        f32x4 sacc[4];
#pragma unroll
        for (int c = 0; c < 4; ++c) sacc[c] = zf;
        __builtin_amdgcn_s_setprio(1);
#pragma unroll
        for (int c = 0; c < 4; ++c) {
            const int kr = c * 16 + lc;
            const int swk = (kr & 7) << 3;
            const bf16x8 kf = *(const bf16x8*)&lds[KO + kr * 64 + ((g * 8) ^ swk)];
            sacc[c] = MFMA16(kf, qB0, sacc[c]);
        }
#pragma unroll
        for (int c = 0; c < 4; ++c) {
            const int kr = c * 16 + lc;
            const int swk = (kr & 7) << 3;
            const bf16x8 kf = *(const bf16x8*)&lds[KO + kr * 64 + ((32 + g * 8) ^ swk)];
            sacc[c] = MFMA16(kf, qB1, sacc[c]);
        }
        __builtin_amdgcn_s_setprio(0);

        // --- defer-max check (no cross-lane data exchange in common path) ---
        float lmax = fmaxf(fmaxf(sacc[0][0], sacc[0][1]), fmaxf(sacc[0][2], sacc[0][3]));
        lmax = fmaxf(lmax, fmaxf(fmaxf(sacc[1][0], sacc[1][1]), fmaxf(sacc[1][2], sacc[1][3])));
        lmax = fmaxf(lmax, fmaxf(fmaxf(sacc[2][0], sacc[2][1]), fmaxf(sacc[2][2], sacc[2][3])));
        lmax = fmaxf(lmax, fmaxf(fmaxf(sacc[3][0], sacc[3][1]), fmaxf(sacc[3][2], sacc[3][3])));
        if (__any(lmax > mrun + 8.0f)) {   // rare after the first tiles
            float mx = lmax;
            mx = fmaxf(mx, __shfl_xor(mx, 16));
            mx = fmaxf(mx, __shfl_xor(mx, 32));
            const float mnew = fmaxf(mrun, mx);
            const float fs = exp2_fast(mrun - mnew);
            lsum *= fs;
            mrun = mnew;
#pragma unroll
            for (int i = 0; i < 4; ++i) {
                const float fsi = __shfl(fs, 4 * g + i, 16);
                oacc[0][i] *= fsi; oacc[1][i] *= fsi;
                oacc[2][i] *= fsi; oacc[3][i] *= fsi;
            }
        }

        // --- exp (base-2, stale max: P <= 2^8) + per-lane partial sum ---
#pragma unroll
        for (int c = 0; c < 4; ++c)
#pragma unroll
            for (int i = 0; i < 4; ++i)
                sacc[c][i] = exp2_fast(sacc[c][i] - mrun);
        lsum += ((sacc[0][0] + sacc[0][1]) + (sacc[0][2] + sacc[0][3]))
              + ((sacc[1][0] + sacc[1][1]) + (sacc[1][2] + sacc[1][3]))
              + ((sacc[2][0] + sacc[2][1]) + (sacc[2][2] + sacc[2][3]))
              + ((sacc[3][0] + sacc[3][1]) + (sacc[3][2] + sacc[3][3]));

        // --- PV in two kv-chunks (P chunk wave-private, overlays Q) ---
#pragma unroll
        for (int hf = 0; hf < 2; ++hf) {
#pragma unroll
            for (int c2 = 0; c2 < 2; ++c2) {
                const int c = hf * 2 + c2;
                uint2 w2;
                w2.x = cvt_pk_bf16(sacc[c][0], sacc[c][1]);
                w2.y = cvt_pk_bf16(sacc[c][2], sacc[c][3]);
                *(uint2*)&lds[pb + ((c2 * 16 + 4 * g) ^ psw)] = w2;
            }
            const bf16x8 pA = *(const bf16x8*)&lds[pb + ((g * 8) ^ psw)];
            __builtin_amdgcn_s_setprio(1);
#pragma unroll
            for (int dt = 0; dt < 4; ++dt) {
                const int vrow = dt * 16 + lc;
                const int swv = (vrow & 7) << 3;
                const bf16x8 vB = *(const bf16x8*)&lds[VO + vrow * 64 + ((hf * 32 + g * 8) ^ swv)];
                oacc[dt] = MFMA16(pA, vB, oacc[dt]);
            }
            __builtin_amdgcn_s_setprio(0);
        }

        // store next V tile into the other buffer (its last readers were
        // barrier-separated at tile tt-1; race-free before this barrier)
        if (tt + 1 < NTH) store_v((tt + 1) & 1);
        __syncthreads();   // ONE barrier: publishes V writes, drains K DMA,
                           // and closes reads of buffers tt before overwrite
    }

    // --- final cross-lane l reduction (once) ---
    float ps = lsum;
    ps += __shfl_xor(ps, 16);
    ps += __shfl_xor(ps, 32);

    // --- flash-merge of the two halves (scratch overlays dead K region) ---
    if (half == 1) {
#pragma unroll
        for (int dt = 0; dt < 4; ++dt)
#pragma unroll
            for (int i = 0; i < 4; ++i)
                ldsf[qg * 1024 + (dt * 4 + i) * 64 + lane] = oacc[dt][i];
        ldsf[4096 + qg * 128 + lane] = mrun;
        ldsf[4096 + qg * 128 + 64 + lane] = ps;
    }
    __syncthreads();
    if (half == 0) {
        const float m2 = ldsf[4096 + qg * 128 + lane];
        const float l2 = ldsf[4096 + qg * 128 + 64 + lane];
        const float mf = fmaxf(mrun, m2);
        const float f1 = exp2_fast(mrun - mf);
        const float f2 = exp2_fast(m2 - mf);
        const float inv = 1.f / (ps * f1 + l2 * f2);
#pragma unroll
        for (int i = 0; i < 4; ++i) {
            const float f1i = __shfl(f1, 4 * g + i, 16);
            const float f2i = __shfl(f2, 4 * g + i, 16);
            const float invi = __shfl(inv, 4 * g + i, 16);
            const int row = q0 + qg * 16 + 4 * g + i;
#pragma unroll
            for (int dt = 0; dt < 4; ++dt) {
                const float o2 = ldsf[qg * 1024 + (dt * 4 + i) * 64 + lane];
                const float x = (oacc[dt][i] * f1i + o2 * f2i) * invi;
                Oh[(size_t)row * E_DIM + h * D_DIM + dt * 16 + lc] = (_Float16)x;
            }
        }
    }
}

// ---------------------------------------------------------------------------
extern "C" void kernel_launch(void* const* d_in, const int* in_sizes, int n_in,
                              void* d_out, int out_size, void* d_ws, size_t ws_size,
                              hipStream_t stream)
{
    (void)in_sizes; (void)n_in; (void)out_size; (void)ws_size;

    const float* qkv   = (const float*)d_in[0];
    const float* w_in  = (const float*)d_in[1];
    const float* b_in  = (const float*)d_in[2];
    const float* w_out = (const float*)d_in[3];
    const float* b_out = (const float*)d_in[4];
    float* out = (float*)d_out;

    unsigned char* ws = (unsigned char*)d_ws;
    _Float16* Wt1 = (_Float16*)(ws);                          // 6.29 MB [3072][1024]
    _Float16* Wt2 = (_Float16*)(ws + 6291456);                // 2.10 MB [1024][1024]
    _Float16* Ah1 = (_Float16*)(ws + 8388608);                // 4.19 MB [2048][1024]
    unsigned short* proj = (unsigned short*)(ws + 16777216);  // 12.58 MB bf16 [2048][3072]
    _Float16* Oh = Ah1;   // reuse: Ah1 dead after gemm1

    // 1) fused prep: convert A to f16 + transpose both weights
    prep_kernel<<<3072, 256, 0, stream>>>(qkv, Ah1, w_in, Wt1, w_out, Wt2);

    // 2) proj = qkv @ w_in + b_in (1-pass f16, bf16 out, q-part pre-scaled)
    gemm_f16_kernel<128, 96, 1, 0><<<512, 256, 0, stream>>>(
        Ah1, Ah1, Wt1, b_in, (void*)proj, S_LEN, 3 * E_DIM, E_DIM, 32);

    // 3) flash attention (K-DMA dbuf + V dbuf, 1 barrier/tile) -> Oh f16
    attn_mfma_kernel<<<512, 512, 0, stream>>>(proj, Oh);

    // 4) out = attn @ w_out + b_out (1-pass f16, fp32 out)
    gemm_f16_kernel<64, 64, 0, 0><<<512, 256, 0, stream>>>(
        Oh, Oh, Wt2, b_out, (void*)out, S_LEN, E_DIM, E_DIM, 16);
}

// Round 21
// 84.868 us; speedup vs baseline: 1.0382x; 1.0382x over previous
//
#include <hip/hip_runtime.h>
#include <math.h>

typedef short bf16x8 __attribute__((ext_vector_type(8)));
typedef _Float16 f16x8 __attribute__((ext_vector_type(8)));
typedef _Float16 f16x4 __attribute__((ext_vector_type(4)));
typedef float f32x4 __attribute__((ext_vector_type(4)));
typedef unsigned short u16x4 __attribute__((ext_vector_type(4)));

#define S_LEN 2048
#define E_DIM 1024
#define H_NUM 16
#define D_DIM 64
#define LDP   (3 * E_DIM)
// softmax scale folded into Q at GEMM1 epilogue: 1/sqrt(64) * log2(e)
#define QSCALE 0.18033688011112042f

#define MFMA16(a, b, c)  __builtin_amdgcn_mfma_f32_16x16x32_bf16((a), (b), (c), 0, 0, 0)
#define MFMA16H(a, b, c) __builtin_amdgcn_mfma_f32_16x16x32_f16((a), (b), (c), 0, 0, 0)

__device__ __forceinline__ unsigned short f2bf(float f) {
    union { float f; unsigned int u; } v; v.f = f;
    unsigned int r = v.u + 0x7FFFu + ((v.u >> 16) & 1u);
    return (unsigned short)(r >> 16);
}
__device__ __forceinline__ float exp2_fast(float x) {
    float r; asm("v_exp_f32 %0, %1" : "=v"(r) : "v"(x)); return r;
}
__device__ __forceinline__ unsigned int cvt_pk_bf16(float lo, float hi) {
    unsigned int r;
    asm("v_cvt_pk_bf16_f32 %0, %1, %2" : "=v"(r) : "v"(lo), "v"(hi));
    return r;
}
// direct global -> LDS, 16B per lane. LDS dest = wave-uniform base + lane*16.
__device__ __forceinline__ void gl_lds16(const void* g, unsigned short* l) {
    __builtin_amdgcn_global_load_lds(
        (const __attribute__((address_space(1))) void*)g,
        (__attribute__((address_space(3))) void*)l, 16, 0, 0);
}

// ---------------------------------------------------------------------------
// Fused prep: [0,2048) convert qkv fp32 -> f16; [2048,2816) transpose w_in;
// [2816,3072) transpose w_out.
// ---------------------------------------------------------------------------
__global__ __launch_bounds__(256) void prep_kernel(
    const float* __restrict__ qkv, _Float16* __restrict__ Ah,
    const float* __restrict__ w_in, _Float16* __restrict__ Wt1,
    const float* __restrict__ w_out, _Float16* __restrict__ Wt2)
{
    __shared__ float tile[64][65];
    const int bid = blockIdx.x;
    const int t = threadIdx.x;

    if (bid < 2048) {
        const int i = bid * 256 + t;
        const float4 v = ((const float4*)qkv)[i];
        f16x4 hh;
        hh[0] = (_Float16)v.x; hh[1] = (_Float16)v.y;
        hh[2] = (_Float16)v.z; hh[3] = (_Float16)v.w;
        ((f16x4*)Ah)[i] = hh;
        return;
    }
    const float* B;
    _Float16* Bt;
    int bx, by, N;
    if (bid < 2816) { B = w_in;  Bt = Wt1; N = 3 * E_DIM; bx = (bid - 2048) % 48; by = (bid - 2048) / 48; }
    else            { B = w_out; Bt = Wt2; N = E_DIM;     bx = (bid - 2816) % 16; by = (bid - 2816) / 16; }
    const int K = E_DIM;
    const int k0 = by * 64, n0 = bx * 64;
    const int r4 = t >> 6, c = t & 63;
#pragma unroll
    for (int rep = 0; rep < 16; ++rep)
        tile[rep * 4 + r4][c] = B[(size_t)(k0 + rep * 4 + r4) * N + n0 + c];
    __syncthreads();
#pragma unroll
    for (int rep = 0; rep < 16; ++rep) {
        const int n = rep * 4 + r4;
        Bt[(size_t)(n0 + n) * K + k0 + c] = (_Float16)tile[c][n];
    }
}

// ---------------------------------------------------------------------------
// f16 MFMA GEMM, global_load_lds staging + LDS double buffer (r10-proven).
// ---------------------------------------------------------------------------
template <int BM, int BN, int OUT_MODE, int TWO_PASS>
__global__ __launch_bounds__(256) void gemm_f16_kernel(
    const _Float16* __restrict__ Ah, const _Float16* __restrict__ Al,
    const _Float16* __restrict__ Bt, const float* __restrict__ bias,
    void* __restrict__ Cout, int M, int N, int K, int nbx)
{
    constexpr int AROWS = TWO_PASS ? 2 * BM : BM;
    constexpr int ROWS = AROWS + BN;
    constexpr int NISS = ROWS / 16;
    constexpr int MI = BM / 32, NI = BN / 32;
    __shared__ unsigned short lds[2 * ROWS * 32];

    const int nwg = gridDim.x;
    const int bid = blockIdx.x;
    const int qch = nwg >> 3;
    const int swz = (bid & 7) * qch + (bid >> 3);
    const int n0 = (swz % nbx) * BN;
    const int m0 = (swz / nbx) * BM;

    const int t = threadIdx.x;
    const int wid = t >> 6, lane = t & 63;
    const int wr = wid >> 1, wc = wid & 1;
    const int lc = lane & 15, g = lane >> 4;
    const int lrow = lane >> 2;
    const int lcol = (lane & 3) * 8;

    f32x4 acc[MI][NI];
    const f32x4 zf = {0.f, 0.f, 0.f, 0.f};
#pragma unroll
    for (int mi = 0; mi < MI; ++mi)
#pragma unroll
        for (int ni = 0; ni < NI; ++ni) acc[mi][ni] = zf;

    auto stage = [&](int k0, int b) {
        unsigned short* base = &lds[b * ROWS * 32];
#pragma unroll
        for (int e = wid; e < NISS; e += 4) {
            const int rb = e * 16;
            const int rr = rb + lrow;
            const _Float16* gp;
            if (rb < BM)                            gp = &Ah[(size_t)(m0 + rr) * K + k0 + lcol];
            else if (TWO_PASS && rb < 2 * BM)       gp = &Al[(size_t)(m0 + rr - BM) * K + k0 + lcol];
            else                                    gp = &Bt[(size_t)(n0 + rr - AROWS) * K + k0 + lcol];
            gl_lds16(gp, base + rb * 32);
        }
    };

    stage(0, 0);
    const int NK = K / 32;
    for (int ks = 0; ks < NK; ++ks) {
        __syncthreads();
        if (ks + 1 < NK) stage((ks + 1) * 32, (ks + 1) & 1);
        const unsigned short* cb = &lds[(ks & 1) * ROWS * 32];

        f16x8 bfr[NI];
#pragma unroll
        for (int ni = 0; ni < NI; ++ni)
            bfr[ni] = *(const f16x8*)&cb[(AROWS + wc * (BN / 2) + ni * 16 + lc) * 32 + g * 8];
#pragma unroll
        for (int mi = 0; mi < MI; ++mi) {
            const int ar = wr * (BM / 2) + mi * 16 + lc;
            const f16x8 ah = *(const f16x8*)&cb[ar * 32 + g * 8];
#pragma unroll
            for (int ni = 0; ni < NI; ++ni)
                acc[mi][ni] = MFMA16H(ah, bfr[ni], acc[mi][ni]);
            if (TWO_PASS) {
                const f16x8 al = *(const f16x8*)&cb[(BM + ar) * 32 + g * 8];
#pragma unroll
                for (int ni = 0; ni < NI; ++ni)
                    acc[mi][ni] = MFMA16H(al, bfr[ni], acc[mi][ni]);
            }
        }
    }

#pragma unroll
    for (int ni = 0; ni < NI; ++ni) {
        const int col = n0 + wc * (BN / 2) + ni * 16 + lc;
        const float bv = bias[col];
        float sc = 1.f;
        if (OUT_MODE == 1) sc = (col < E_DIM) ? QSCALE : 1.f;
#pragma unroll
        for (int mi = 0; mi < MI; ++mi) {
            const int rbase = m0 + wr * (BM / 2) + mi * 16 + g * 4;
#pragma unroll
            for (int i = 0; i < 4; ++i) {
                const float v = acc[mi][ni][i] + bv;
                if (OUT_MODE == 1)
                    ((unsigned short*)Cout)[(size_t)(rbase + i) * N + col] = f2bf(v * sc);
                else
                    ((float*)Cout)[(size_t)(rbase + i) * N + col] = v;
            }
        }
    }
}

// ---------------------------------------------------------------------------
// MFMA flash attention (r19, best measured): r10 structure with K staged via
// global_load_lds DMA into a DOUBLE-buffered K region (pre-swizzled source,
// linear dest). DMA for tile tt+1 issues at the TOP of tile tt into the
// other buffer, so the barrier's vmcnt drain finds it complete. V keeps the
// proven reg-transpose single-buffer path (r20 showed merging the V-publish
// barrier into one per tile regresses: the single drain point then covers
// the fresh V global loads too).
// Block = 64 Q rows x head, 8 waves: waves 0-3 kv[0,1024), 4-7 kv[1024,2048).
// LDS: K 2x2x8KB | V 2x8KB | Q/P 8KB = 56KB -> 2 blocks/CU (grid-limited).
// ---------------------------------------------------------------------------
__global__ __launch_bounds__(512, 4) void attn_mfma_kernel(
    const unsigned short* __restrict__ proj, _Float16* __restrict__ Oh)
{
    // elems: K [2 half][2 buf][64][64] @0 | Vt [2 half][64][64] @16384
    //        Q/P @24576
    __shared__ unsigned short lds[28672];   // 56 KB
    float* ldsf = (float*)lds;              // merge scratch overlays dead K
    const int QP = 24576;

    const int t = threadIdx.x;
    const int w = t >> 6, lane = t & 63;
    const int lc = lane & 15, g = lane >> 4;
    const int qg = w & 3;        // q-row group (16 rows)
    const int half = w >> 2;     // kv half
    const int ts = t & 255;

    const int bid = blockIdx.x;
    const int swb = (bid & 7) * 64 + (bid >> 3);
    const int qt = swb & 31;
    const int h  = swb >> 5;
    const int q0 = qt * 64;

    const size_t qoff = (size_t)h * D_DIM;
    const size_t koff = E_DIM + (size_t)h * D_DIM;
    const size_t voff = 2 * E_DIM + (size_t)h * D_DIM;

    const int KH = half * 8192;          // K base for this half (2 bufs)
    const int VO = 16384 + half * 4096;  // V base for this half
    const int kvbase = half * (S_LEN / 2);

    // V staging coords (within 256-thread half-group)
    const int r  = ts >> 2;           // 0..63 (also used for Q staging)
    const int s  = (ts & 3) * 16;
    const int sw = (r & 7) << 3;
    const int kv = (ts & 15) * 4;     // V-transpose src rows
    const int d0 = (ts >> 4) * 4;     // V-transpose dst rows

    u16x4 vr[4];
    auto load_v = [&](int tile) {
        const int t0 = kvbase + tile * 64;
#pragma unroll
        for (int r2 = 0; r2 < 4; ++r2)
            vr[r2] = *(const u16x4*)&proj[(size_t)(t0 + kv + r2) * LDP + voff + d0];
    };
    auto store_v = [&]() {
#pragma unroll
        for (int j = 0; j < 4; ++j) {
            u16x4 w4; w4[0] = vr[0][j]; w4[1] = vr[1][j]; w4[2] = vr[2][j]; w4[3] = vr[3][j];
            const int d = d0 + j;
            *(u16x4*)&lds[VO + d * 64 + (kv ^ ((d & 7) << 3))] = w4;
        }
    };

    // K staging: gl_lds DMA, pre-swizzled source, linear dest (r13-proven).
    // Per half: 4 waves x 2 issues x 8 rows = 64 rows.
    const int klr = lane >> 3, ksl = lane & 7;
    const int ksrc = (ksl ^ klr) * 8;
    const int wh = w & 3;               // wave index within half
    auto stage_k = [&](int tile, int buf) {
        const int t0 = kvbase + tile * 64;
        unsigned short* kb = &lds[KH + buf * 4096];
#pragma unroll
        for (int e = 0; e < 2; ++e) {
            const int rb = (wh * 2 + e) * 8;
            gl_lds16(&proj[(size_t)(t0 + rb + klr) * LDP + koff + ksrc],
                     kb + rb * 64);
        }
    };

    // --- prologue: K tile 0 via DMA, V tile 0 via regs, Q staged (group 0) ---
    stage_k(0, 0);
    if (half == 0) {
        const unsigned short* gq = &proj[(size_t)(q0 + r) * LDP + qoff + s];
        const uint4 v0 = ((const uint4*)gq)[0];
        const uint4 v1 = ((const uint4*)gq)[1];
        *(uint4*)&lds[QP + r * 64 + (s ^ sw)]       = v0;
        *(uint4*)&lds[QP + r * 64 + ((s + 8) ^ sw)] = v1;
    }
    load_v(0);
    store_v();
    __syncthreads();   // drains K DMA (vmcnt) + Q/V ds_writes

    // hoist Q fragments: lane owns q-row qg*16+lc
    bf16x8 qB0, qB1;
    {
        const int rq = qg * 16 + lc;
        const int swq = (rq & 7) << 3;
        qB0 = *(const bf16x8*)&lds[QP + rq * 64 + ((g * 8) ^ swq)];
        qB1 = *(const bf16x8*)&lds[QP + rq * 64 + ((32 + g * 8) ^ swq)];
    }
    __syncthreads();   // all waves hoisted Q before P overlays the region

    f32x4 oacc[4];
    const f32x4 zf = {0.f, 0.f, 0.f, 0.f};
#pragma unroll
    for (int i = 0; i < 4; ++i) oacc[i] = zf;
    float mrun = -1e30f;   // defer-max high-water mark (T13)
    float lsum = 0.f;      // per-lane partial sum (reduced after loop)

    // per-wave P chunk: 16 rows x 32 kv-cols, overlaid on Q region.
    const int pb = QP + w * 512 + lc * 32;
    const int psw = ((lc >> 1) & 3) << 3;

    const int NTH = (S_LEN / 2) / 64;   // 16 tiles per half
    for (int tt = 0; tt < NTH; ++tt) {
        // issue next tile: K DMA into other buffer; V into regs (T14)
        if (tt + 1 < NTH) {
            stage_k(tt + 1, (tt + 1) & 1);
            load_v(tt + 1);
        }
        const int KO = KH + (tt & 1) * 4096;

        // --- QK^T (swapped: A=K, B=Q): sacc[c][i] = S[kv=c*16+4g+i][q=lc] ---
        f32x4 sacc[4];
#pragma unroll
        for (int c = 0; c < 4; ++c) sacc[c] = zf;
        __builtin_amdgcn_s_setprio(1);
#pragma unroll
        for (int c = 0; c < 4; ++c) {
            const int kr = c * 16 + lc;
            const int swk = (kr & 7) << 3;
            const bf16x8 kf = *(const bf16x8*)&lds[KO + kr * 64 + ((g * 8) ^ swk)];
            sacc[c] = MFMA16(kf, qB0, sacc[c]);
        }
#pragma unroll
        for (int c = 0; c < 4; ++c) {
            const int kr = c * 16 + lc;
            const int swk = (kr & 7) << 3;
            const bf16x8 kf = *(const bf16x8*)&lds[KO + kr * 64 + ((32 + g * 8) ^ swk)];
            sacc[c] = MFMA16(kf, qB1, sacc[c]);
        }
        __builtin_amdgcn_s_setprio(0);

        // --- defer-max check (no cross-lane data exchange in common path) ---
        float lmax = fmaxf(fmaxf(sacc[0][0], sacc[0][1]), fmaxf(sacc[0][2], sacc[0][3]));
        lmax = fmaxf(lmax, fmaxf(fmaxf(sacc[1][0], sacc[1][1]), fmaxf(sacc[1][2], sacc[1][3])));
        lmax = fmaxf(lmax, fmaxf(fmaxf(sacc[2][0], sacc[2][1]), fmaxf(sacc[2][2], sacc[2][3])));
        lmax = fmaxf(lmax, fmaxf(fmaxf(sacc[3][0], sacc[3][1]), fmaxf(sacc[3][2], sacc[3][3])));
        if (__any(lmax > mrun + 8.0f)) {   // rare after the first tiles
            float mx = lmax;
            mx = fmaxf(mx, __shfl_xor(mx, 16));
            mx = fmaxf(mx, __shfl_xor(mx, 32));
            const float mnew = fmaxf(mrun, mx);
            const float fs = exp2_fast(mrun - mnew);
            lsum *= fs;
            mrun = mnew;
#pragma unroll
            for (int i = 0; i < 4; ++i) {
                const float fsi = __shfl(fs, 4 * g + i, 16);
                oacc[0][i] *= fsi; oacc[1][i] *= fsi;
                oacc[2][i] *= fsi; oacc[3][i] *= fsi;
            }
        }

        // --- exp (base-2, stale max: P <= 2^8) + per-lane partial sum ---
#pragma unroll
        for (int c = 0; c < 4; ++c)
#pragma unroll
            for (int i = 0; i < 4; ++i)
                sacc[c][i] = exp2_fast(sacc[c][i] - mrun);
        lsum += ((sacc[0][0] + sacc[0][1]) + (sacc[0][2] + sacc[0][3]))
              + ((sacc[1][0] + sacc[1][1]) + (sacc[1][2] + sacc[1][3]))
              + ((sacc[2][0] + sacc[2][1]) + (sacc[2][2] + sacc[2][3]))
              + ((sacc[3][0] + sacc[3][1]) + (sacc[3][2] + sacc[3][3]));

        // --- PV in two kv-chunks (P chunk wave-private, overlays Q) ---
#pragma unroll
        for (int hf = 0; hf < 2; ++hf) {
#pragma unroll
            for (int c2 = 0; c2 < 2; ++c2) {
                const int c = hf * 2 + c2;
                uint2 w2;
                w2.x = cvt_pk_bf16(sacc[c][0], sacc[c][1]);
                w2.y = cvt_pk_bf16(sacc[c][2], sacc[c][3]);
                *(uint2*)&lds[pb + ((c2 * 16 + 4 * g) ^ psw)] = w2;
            }
            const bf16x8 pA = *(const bf16x8*)&lds[pb + ((g * 8) ^ psw)];
            __builtin_amdgcn_s_setprio(1);
#pragma unroll
            for (int dt = 0; dt < 4; ++dt) {
                const int vrow = dt * 16 + lc;
                const int swv = (vrow & 7) << 3;
                const bf16x8 vB = *(const bf16x8*)&lds[VO + vrow * 64 + ((hf * 32 + g * 8) ^ swv)];
                oacc[dt] = MFMA16(pA, vB, oacc[dt]);
            }
            __builtin_amdgcn_s_setprio(0);
        }

        __syncthreads();                 // all waves done reading K/V
        if (tt + 1 < NTH) {
            store_v();                   // V regs (loaded during compute) -> LDS
            __syncthreads();             // publishes V writes; drains K DMA
        }
    }

    // --- final cross-lane l reduction (once) ---
    float ps = lsum;
    ps += __shfl_xor(ps, 16);
    ps += __shfl_xor(ps, 32);

    // --- flash-merge of the two halves (scratch overlays dead K region) ---
    if (half == 1) {
#pragma unroll
        for (int dt = 0; dt < 4; ++dt)
#pragma unroll
            for (int i = 0; i < 4; ++i)
                ldsf[qg * 1024 + (dt * 4 + i) * 64 + lane] = oacc[dt][i];
        ldsf[4096 + qg * 128 + lane] = mrun;
        ldsf[4096 + qg * 128 + 64 + lane] = ps;
    }
    __syncthreads();
    if (half == 0) {
        const float m2 = ldsf[4096 + qg * 128 + lane];
        const float l2 = ldsf[4096 + qg * 128 + 64 + lane];
        const float mf = fmaxf(mrun, m2);
        const float f1 = exp2_fast(mrun - mf);
        const float f2 = exp2_fast(m2 - mf);
        const float inv = 1.f / (ps * f1 + l2 * f2);
#pragma unroll
        for (int i = 0; i < 4; ++i) {
            const float f1i = __shfl(f1, 4 * g + i, 16);
            const float f2i = __shfl(f2, 4 * g + i, 16);
            const float invi = __shfl(inv, 4 * g + i, 16);
            const int row = q0 + qg * 16 + 4 * g + i;
#pragma unroll
            for (int dt = 0; dt < 4; ++dt) {
                const float o2 = ldsf[qg * 1024 + (dt * 4 + i) * 64 + lane];
                const float x = (oacc[dt][i] * f1i + o2 * f2i) * invi;
                Oh[(size_t)row * E_DIM + h * D_DIM + dt * 16 + lc] = (_Float16)x;
            }
        }
    }
}

// ---------------------------------------------------------------------------
extern "C" void kernel_launch(void* const* d_in, const int* in_sizes, int n_in,
                              void* d_out, int out_size, void* d_ws, size_t ws_size,
                              hipStream_t stream)
{
    (void)in_sizes; (void)n_in; (void)out_size; (void)ws_size;

    const float* qkv   = (const float*)d_in[0];
    const float* w_in  = (const float*)d_in[1];
    const float* b_in  = (const float*)d_in[2];
    const float* w_out = (const float*)d_in[3];
    const float* b_out = (const float*)d_in[4];
    float* out = (float*)d_out;

    unsigned char* ws = (unsigned char*)d_ws;
    _Float16* Wt1 = (_Float16*)(ws);                          // 6.29 MB [3072][1024]
    _Float16* Wt2 = (_Float16*)(ws + 6291456);                // 2.10 MB [1024][1024]
    _Float16* Ah1 = (_Float16*)(ws + 8388608);                // 4.19 MB [2048][1024]
    unsigned short* proj = (unsigned short*)(ws + 16777216);  // 12.58 MB bf16 [2048][3072]
    _Float16* Oh = Ah1;   // reuse: Ah1 dead after gemm1

    // 1) fused prep: convert A to f16 + transpose both weights
    prep_kernel<<<3072, 256, 0, stream>>>(qkv, Ah1, w_in, Wt1, w_out, Wt2);

    // 2) proj = qkv @ w_in + b_in (1-pass f16, bf16 out, q-part pre-scaled)
    gemm_f16_kernel<128, 96, 1, 0><<<512, 256, 0, stream>>>(
        Ah1, Ah1, Wt1, b_in, (void*)proj, S_LEN, 3 * E_DIM, E_DIM, 32);

    // 3) flash attention (r19: K-DMA double buffer, 2-barrier tiles) -> Oh f16
    attn_mfma_kernel<<<512, 512, 0, stream>>>(proj, Oh);

    // 4) out = attn @ w_out + b_out (1-pass f16, fp32 out)
    gemm_f16_kernel<64, 64, 0, 0><<<512, 256, 0, stream>>>(
        Oh, Oh, Wt2, b_out, (void*)out, S_LEN, E_DIM, E_DIM, 16);
}

// Round 22
// 79.442 us; speedup vs baseline: 1.1091x; 1.0683x over previous
//
#include <hip/hip_runtime.h>
#include <math.h>

typedef short bf16x8 __attribute__((ext_vector_type(8)));
typedef _Float16 f16x8 __attribute__((ext_vector_type(8)));
typedef _Float16 f16x4 __attribute__((ext_vector_type(4)));
typedef float f32x4 __attribute__((ext_vector_type(4)));
typedef unsigned short u16x4 __attribute__((ext_vector_type(4)));

#define S_LEN 2048
#define E_DIM 1024
#define H_NUM 16
#define D_DIM 64
#define LDP   (3 * E_DIM)
// softmax scale folded into Q at GEMM1 epilogue: 1/sqrt(64) * log2(e)
#define QSCALE 0.18033688011112042f

#define MFMA16(a, b, c)  __builtin_amdgcn_mfma_f32_16x16x32_bf16((a), (b), (c), 0, 0, 0)
#define MFMA16H(a, b, c) __builtin_amdgcn_mfma_f32_16x16x32_f16((a), (b), (c), 0, 0, 0)

__device__ __forceinline__ unsigned short f2bf(float f) {
    union { float f; unsigned int u; } v; v.f = f;
    unsigned int r = v.u + 0x7FFFu + ((v.u >> 16) & 1u);
    return (unsigned short)(r >> 16);
}
__device__ __forceinline__ float exp2_fast(float x) {
    float r; asm("v_exp_f32 %0, %1" : "=v"(r) : "v"(x)); return r;
}
__device__ __forceinline__ unsigned int cvt_pk_bf16(float lo, float hi) {
    unsigned int r;
    asm("v_cvt_pk_bf16_f32 %0, %1, %2" : "=v"(r) : "v"(lo), "v"(hi));
    return r;
}
// direct global -> LDS, 16B per lane. LDS dest = wave-uniform base + lane*16.
__device__ __forceinline__ void gl_lds16(const void* g, unsigned short* l) {
    __builtin_amdgcn_global_load_lds(
        (const __attribute__((address_space(1))) void*)g,
        (__attribute__((address_space(3))) void*)l, 16, 0, 0);
}

// ---------------------------------------------------------------------------
// Fused prep: [0,2048) convert qkv fp32 -> f16; [2048,2816) transpose w_in;
// [2816,3072) transpose w_out.
// ---------------------------------------------------------------------------
__global__ __launch_bounds__(256) void prep_kernel(
    const float* __restrict__ qkv, _Float16* __restrict__ Ah,
    const float* __restrict__ w_in, _Float16* __restrict__ Wt1,
    const float* __restrict__ w_out, _Float16* __restrict__ Wt2)
{
    __shared__ float tile[64][65];
    const int bid = blockIdx.x;
    const int t = threadIdx.x;

    if (bid < 2048) {
        const int i = bid * 256 + t;
        const float4 v = ((const float4*)qkv)[i];
        f16x4 hh;
        hh[0] = (_Float16)v.x; hh[1] = (_Float16)v.y;
        hh[2] = (_Float16)v.z; hh[3] = (_Float16)v.w;
        ((f16x4*)Ah)[i] = hh;
        return;
    }
    const float* B;
    _Float16* Bt;
    int bx, by, N;
    if (bid < 2816) { B = w_in;  Bt = Wt1; N = 3 * E_DIM; bx = (bid - 2048) % 48; by = (bid - 2048) / 48; }
    else            { B = w_out; Bt = Wt2; N = E_DIM;     bx = (bid - 2816) % 16; by = (bid - 2816) / 16; }
    const int K = E_DIM;
    const int k0 = by * 64, n0 = bx * 64;
    const int r4 = t >> 6, c = t & 63;
#pragma unroll
    for (int rep = 0; rep < 16; ++rep)
        tile[rep * 4 + r4][c] = B[(size_t)(k0 + rep * 4 + r4) * N + n0 + c];
    __syncthreads();
#pragma unroll
    for (int rep = 0; rep < 16; ++rep) {
        const int n = rep * 4 + r4;
        Bt[(size_t)(n0 + n) * K + k0 + c] = (_Float16)tile[c][n];
    }
}

// ---------------------------------------------------------------------------
// f16 MFMA GEMM, BK=64: global_load_lds staging with PRE-SWIZZLED source
// (m173 pattern; LDS rows 128B, read chunk (kk*4+g)^(row&7) -> <=2-way
// banks) + LDS double buffer. Halves barrier count vs BK=32 at unchanged
// occupancy (grid-capped 2 blocks/CU).
// TWO_PASS=1: C = (Ah+Al) @ Bt^T + bias;  TWO_PASS=0: C = Ah @ Bt^T + bias.
// ---------------------------------------------------------------------------
template <int BM, int BN, int OUT_MODE, int TWO_PASS>
__global__ __launch_bounds__(256) void gemm_f16_kernel(
    const _Float16* __restrict__ Ah, const _Float16* __restrict__ Al,
    const _Float16* __restrict__ Bt, const float* __restrict__ bias,
    void* __restrict__ Cout, int M, int N, int K, int nbx)
{
    constexpr int AROWS = TWO_PASS ? 2 * BM : BM;
    constexpr int ROWS = AROWS + BN;     // rows of 64 f16 (128B)
    constexpr int NISS = ROWS / 8;       // 8-row gl_lds issues per stage
    constexpr int MI = BM / 32, NI = BN / 32;
    __shared__ unsigned short lds[2 * ROWS * 64];

    const int nwg = gridDim.x;
    const int bid = blockIdx.x;
    const int qch = nwg >> 3;
    const int swz = (bid & 7) * qch + (bid >> 3);
    const int n0 = (swz % nbx) * BN;
    const int m0 = (swz / nbx) * BM;

    const int t = threadIdx.x;
    const int wid = t >> 6, lane = t & 63;
    const int wr = wid >> 1, wc = wid & 1;
    const int lc = lane & 15, g = lane >> 4;
    const int klr = lane >> 3, ksl = lane & 7;
    const int ksrc = (ksl ^ klr) * 8;    // pre-swizzled source col (f16)

    f32x4 acc[MI][NI];
    const f32x4 zf = {0.f, 0.f, 0.f, 0.f};
#pragma unroll
    for (int mi = 0; mi < MI; ++mi)
#pragma unroll
        for (int ni = 0; ni < NI; ++ni) acc[mi][ni] = zf;

    auto stage = [&](int k0, int b) {
        unsigned short* base = &lds[b * ROWS * 64];
#pragma unroll
        for (int e = wid; e < NISS; e += 4) {
            const int rb = e * 8;
            const int rr = rb + klr;
            const _Float16* gp;
            if (rb < BM)                      gp = &Ah[(size_t)(m0 + rr) * K + k0 + ksrc];
            else if (TWO_PASS && rb < 2 * BM) gp = &Al[(size_t)(m0 + rr - BM) * K + k0 + ksrc];
            else                              gp = &Bt[(size_t)(n0 + rr - AROWS) * K + k0 + ksrc];
            gl_lds16(gp, base + rb * 64);
        }
    };

    stage(0, 0);
    const int NK = K / 64;
    for (int ks = 0; ks < NK; ++ks) {
        __syncthreads();
        if (ks + 1 < NK) stage((ks + 1) * 64, (ks + 1) & 1);
        const unsigned short* cb = &lds[(ks & 1) * ROWS * 64];

#pragma unroll
        for (int kk = 0; kk < 2; ++kk) {
            f16x8 bfr[NI];
#pragma unroll
            for (int ni = 0; ni < NI; ++ni) {
                const int br = AROWS + wc * (BN / 2) + ni * 16 + lc;
                bfr[ni] = *(const f16x8*)&cb[br * 64 + (((kk * 4 + g) ^ (br & 7)) * 8)];
            }
#pragma unroll
            for (int mi = 0; mi < MI; ++mi) {
                const int ar = wr * (BM / 2) + mi * 16 + lc;
                const f16x8 ah = *(const f16x8*)&cb[ar * 64 + (((kk * 4 + g) ^ (ar & 7)) * 8)];
#pragma unroll
                for (int ni = 0; ni < NI; ++ni)
                    acc[mi][ni] = MFMA16H(ah, bfr[ni], acc[mi][ni]);
                if (TWO_PASS) {
                    const int alr = BM + ar;   // BM multiple of 8: (alr&7)==(ar&7)
                    const f16x8 al = *(const f16x8*)&cb[alr * 64 + (((kk * 4 + g) ^ (alr & 7)) * 8)];
#pragma unroll
                    for (int ni = 0; ni < NI; ++ni)
                        acc[mi][ni] = MFMA16H(al, bfr[ni], acc[mi][ni]);
                }
            }
        }
    }

#pragma unroll
    for (int ni = 0; ni < NI; ++ni) {
        const int col = n0 + wc * (BN / 2) + ni * 16 + lc;
        const float bv = bias[col];
        float sc = 1.f;
        if (OUT_MODE == 1) sc = (col < E_DIM) ? QSCALE : 1.f;
#pragma unroll
        for (int mi = 0; mi < MI; ++mi) {
            const int rbase = m0 + wr * (BM / 2) + mi * 16 + g * 4;
#pragma unroll
            for (int i = 0; i < 4; ++i) {
                const float v = acc[mi][ni][i] + bv;
                if (OUT_MODE == 1)
                    ((unsigned short*)Cout)[(size_t)(rbase + i) * N + col] = f2bf(v * sc);
                else
                    ((float*)Cout)[(size_t)(rbase + i) * N + col] = v;
            }
        }
    }
}

// ---------------------------------------------------------------------------
// MFMA flash attention (r19/r21, best measured, 3x reproduced): r10 structure
// with K staged via global_load_lds DMA into a DOUBLE-buffered K region
// (pre-swizzled source, linear dest). V keeps reg-transpose single buffer.
// Block = 64 Q rows x head, 8 waves: waves 0-3 kv[0,1024), 4-7 kv[1024,2048).
// LDS: K 2x2x8KB | V 2x8KB | Q/P 8KB = 56KB -> 2 blocks/CU (grid-limited).
// ---------------------------------------------------------------------------
__global__ __launch_bounds__(512, 4) void attn_mfma_kernel(
    const unsigned short* __restrict__ proj, _Float16* __restrict__ Oh)
{
    // elems: K [2 half][2 buf][64][64] @0 | Vt [2 half][64][64] @16384
    //        Q/P @24576
    __shared__ unsigned short lds[28672];   // 56 KB
    float* ldsf = (float*)lds;              // merge scratch overlays dead K
    const int QP = 24576;

    const int t = threadIdx.x;
    const int w = t >> 6, lane = t & 63;
    const int lc = lane & 15, g = lane >> 4;
    const int qg = w & 3;        // q-row group (16 rows)
    const int half = w >> 2;     // kv half
    const int ts = t & 255;

    const int bid = blockIdx.x;
    const int swb = (bid & 7) * 64 + (bid >> 3);
    const int qt = swb & 31;
    const int h  = swb >> 5;
    const int q0 = qt * 64;

    const size_t qoff = (size_t)h * D_DIM;
    const size_t koff = E_DIM + (size_t)h * D_DIM;
    const size_t voff = 2 * E_DIM + (size_t)h * D_DIM;

    const int KH = half * 8192;          // K base for this half (2 bufs)
    const int VO = 16384 + half * 4096;  // V base for this half
    const int kvbase = half * (S_LEN / 2);

    // V staging coords (within 256-thread half-group)
    const int r  = ts >> 2;           // 0..63 (also used for Q staging)
    const int s  = (ts & 3) * 16;
    const int sw = (r & 7) << 3;
    const int kv = (ts & 15) * 4;     // V-transpose src rows
    const int d0 = (ts >> 4) * 4;     // V-transpose dst rows

    u16x4 vr[4];
    auto load_v = [&](int tile) {
        const int t0 = kvbase + tile * 64;
#pragma unroll
        for (int r2 = 0; r2 < 4; ++r2)
            vr[r2] = *(const u16x4*)&proj[(size_t)(t0 + kv + r2) * LDP + voff + d0];
    };
    auto store_v = [&]() {
#pragma unroll
        for (int j = 0; j < 4; ++j) {
            u16x4 w4; w4[0] = vr[0][j]; w4[1] = vr[1][j]; w4[2] = vr[2][j]; w4[3] = vr[3][j];
            const int d = d0 + j;
            *(u16x4*)&lds[VO + d * 64 + (kv ^ ((d & 7) << 3))] = w4;
        }
    };

    // K staging: gl_lds DMA, pre-swizzled source, linear dest (r13-proven).
    const int klr = lane >> 3, ksl = lane & 7;
    const int ksrc = (ksl ^ klr) * 8;
    const int wh = w & 3;               // wave index within half
    auto stage_k = [&](int tile, int buf) {
        const int t0 = kvbase + tile * 64;
        unsigned short* kb = &lds[KH + buf * 4096];
#pragma unroll
        for (int e = 0; e < 2; ++e) {
            const int rb = (wh * 2 + e) * 8;
            gl_lds16(&proj[(size_t)(t0 + rb + klr) * LDP + koff + ksrc],
                     kb + rb * 64);
        }
    };

    // --- prologue: K tile 0 via DMA, V tile 0 via regs, Q staged (group 0) ---
    stage_k(0, 0);
    if (half == 0) {
        const unsigned short* gq = &proj[(size_t)(q0 + r) * LDP + qoff + s];
        const uint4 v0 = ((const uint4*)gq)[0];
        const uint4 v1 = ((const uint4*)gq)[1];
        *(uint4*)&lds[QP + r * 64 + (s ^ sw)]       = v0;
        *(uint4*)&lds[QP + r * 64 + ((s + 8) ^ sw)] = v1;
    }
    load_v(0);
    store_v();
    __syncthreads();   // drains K DMA (vmcnt) + Q/V ds_writes

    // hoist Q fragments: lane owns q-row qg*16+lc
    bf16x8 qB0, qB1;
    {
        const int rq = qg * 16 + lc;
        const int swq = (rq & 7) << 3;
        qB0 = *(const bf16x8*)&lds[QP + rq * 64 + ((g * 8) ^ swq)];
        qB1 = *(const bf16x8*)&lds[QP + rq * 64 + ((32 + g * 8) ^ swq)];
    }
    __syncthreads();   // all waves hoisted Q before P overlays the region

    f32x4 oacc[4];
    const f32x4 zf = {0.f, 0.f, 0.f, 0.f};
#pragma unroll
    for (int i = 0; i < 4; ++i) oacc[i] = zf;
    float mrun = -1e30f;   // defer-max high-water mark (T13)
    float lsum = 0.f;      // per-lane partial sum (reduced after loop)

    // per-wave P chunk: 16 rows x 32 kv-cols, overlaid on Q region.
    const int pb = QP + w * 512 + lc * 32;
    const int psw = ((lc >> 1) & 3) << 3;

    const int NTH = (S_LEN / 2) / 64;   // 16 tiles per half
    for (int tt = 0; tt < NTH; ++tt) {
        // issue next tile: K DMA into other buffer; V into regs (T14)
        if (tt + 1 < NTH) {
            stage_k(tt + 1, (tt + 1) & 1);
            load_v(tt + 1);
        }
        const int KO = KH + (tt & 1) * 4096;

        // --- QK^T (swapped: A=K, B=Q): sacc[c][i] = S[kv=c*16+4g+i][q=lc] ---
        f32x4 sacc[4];
#pragma unroll
        for (int c = 0; c < 4; ++c) sacc[c] = zf;
        __builtin_amdgcn_s_setprio(1);
#pragma unroll
        for (int c = 0; c < 4; ++c) {
            const int kr = c * 16 + lc;
            const int swk = (kr & 7) << 3;
            const bf16x8 kf = *(const bf16x8*)&lds[KO + kr * 64 + ((g * 8) ^ swk)];
            sacc[c] = MFMA16(kf, qB0, sacc[c]);
        }
#pragma unroll
        for (int c = 0; c < 4; ++c) {
            const int kr = c * 16 + lc;
            const int swk = (kr & 7) << 3;
            const bf16x8 kf = *(const bf16x8*)&lds[KO + kr * 64 + ((32 + g * 8) ^ swk)];
            sacc[c] = MFMA16(kf, qB1, sacc[c]);
        }
        __builtin_amdgcn_s_setprio(0);

        // --- defer-max check (no cross-lane data exchange in common path) ---
        float lmax = fmaxf(fmaxf(sacc[0][0], sacc[0][1]), fmaxf(sacc[0][2], sacc[0][3]));
        lmax = fmaxf(lmax, fmaxf(fmaxf(sacc[1][0], sacc[1][1]), fmaxf(sacc[1][2], sacc[1][3])));
        lmax = fmaxf(lmax, fmaxf(fmaxf(sacc[2][0], sacc[2][1]), fmaxf(sacc[2][2], sacc[2][3])));
        lmax = fmaxf(lmax, fmaxf(fmaxf(sacc[3][0], sacc[3][1]), fmaxf(sacc[3][2], sacc[3][3])));
        if (__any(lmax > mrun + 8.0f)) {   // rare after the first tiles
            float mx = lmax;
            mx = fmaxf(mx, __shfl_xor(mx, 16));
            mx = fmaxf(mx, __shfl_xor(mx, 32));
            const float mnew = fmaxf(mrun, mx);
            const float fs = exp2_fast(mrun - mnew);
            lsum *= fs;
            mrun = mnew;
#pragma unroll
            for (int i = 0; i < 4; ++i) {
                const float fsi = __shfl(fs, 4 * g + i, 16);
                oacc[0][i] *= fsi; oacc[1][i] *= fsi;
                oacc[2][i] *= fsi; oacc[3][i] *= fsi;
            }
        }

        // --- exp (base-2, stale max: P <= 2^8) + per-lane partial sum ---
#pragma unroll
        for (int c = 0; c < 4; ++c)
#pragma unroll
            for (int i = 0; i < 4; ++i)
                sacc[c][i] = exp2_fast(sacc[c][i] - mrun);
        lsum += ((sacc[0][0] + sacc[0][1]) + (sacc[0][2] + sacc[0][3]))
              + ((sacc[1][0] + sacc[1][1]) + (sacc[1][2] + sacc[1][3]))
              + ((sacc[2][0] + sacc[2][1]) + (sacc[2][2] + sacc[2][3]))
              + ((sacc[3][0] + sacc[3][1]) + (sacc[3][2] + sacc[3][3]));

        // --- PV in two kv-chunks (P chunk wave-private, overlays Q) ---
#pragma unroll
        for (int hf = 0; hf < 2; ++hf) {
#pragma unroll
            for (int c2 = 0; c2 < 2; ++c2) {
                const int c = hf * 2 + c2;
                uint2 w2;
                w2.x = cvt_pk_bf16(sacc[c][0], sacc[c][1]);
                w2.y = cvt_pk_bf16(sacc[c][2], sacc[c][3]);
                *(uint2*)&lds[pb + ((c2 * 16 + 4 * g) ^ psw)] = w2;
            }
            const bf16x8 pA = *(const bf16x8*)&lds[pb + ((g * 8) ^ psw)];
            __builtin_amdgcn_s_setprio(1);
#pragma unroll
            for (int dt = 0; dt < 4; ++dt) {
                const int vrow = dt * 16 + lc;
                const int swv = (vrow & 7) << 3;
                const bf16x8 vB = *(const bf16x8*)&lds[VO + vrow * 64 + ((hf * 32 + g * 8) ^ swv)];
                oacc[dt] = MFMA16(pA, vB, oacc[dt]);
            }
            __builtin_amdgcn_s_setprio(0);
        }

        __syncthreads();                 // all waves done reading K/V
        if (tt + 1 < NTH) {
            store_v();                   // V regs (loaded during compute) -> LDS
            __syncthreads();             // publishes V writes; drains K DMA
        }
    }

    // --- final cross-lane l reduction (once) ---
    float ps = lsum;
    ps += __shfl_xor(ps, 16);
    ps += __shfl_xor(ps, 32);

    // --- flash-merge of the two halves (scratch overlays dead K region) ---
    if (half == 1) {
#pragma unroll
        for (int dt = 0; dt < 4; ++dt)
#pragma unroll
            for (int i = 0; i < 4; ++i)
                ldsf[qg * 1024 + (dt * 4 + i) * 64 + lane] = oacc[dt][i];
        ldsf[4096 + qg * 128 + lane] = mrun;
        ldsf[4096 + qg * 128 + 64 + lane] = ps;
    }
    __syncthreads();
    if (half == 0) {
        const float m2 = ldsf[4096 + qg * 128 + lane];
        const float l2 = ldsf[4096 + qg * 128 + 64 + lane];
        const float mf = fmaxf(mrun, m2);
        const float f1 = exp2_fast(mrun - mf);
        const float f2 = exp2_fast(m2 - mf);
        const float inv = 1.f / (ps * f1 + l2 * f2);
#pragma unroll
        for (int i = 0; i < 4; ++i) {
            const float f1i = __shfl(f1, 4 * g + i, 16);
            const float f2i = __shfl(f2, 4 * g + i, 16);
            const float invi = __shfl(inv, 4 * g + i, 16);
            const int row = q0 + qg * 16 + 4 * g + i;
#pragma unroll
            for (int dt = 0; dt < 4; ++dt) {
                const float o2 = ldsf[qg * 1024 + (dt * 4 + i) * 64 + lane];
                const float x = (oacc[dt][i] * f1i + o2 * f2i) * invi;
                Oh[(size_t)row * E_DIM + h * D_DIM + dt * 16 + lc] = (_Float16)x;
            }
        }
    }
}

// ---------------------------------------------------------------------------
extern "C" void kernel_launch(void* const* d_in, const int* in_sizes, int n_in,
                              void* d_out, int out_size, void* d_ws, size_t ws_size,
                              hipStream_t stream)
{
    (void)in_sizes; (void)n_in; (void)out_size; (void)ws_size;

    const float* qkv   = (const float*)d_in[0];
    const float* w_in  = (const float*)d_in[1];
    const float* b_in  = (const float*)d_in[2];
    const float* w_out = (const float*)d_in[3];
    const float* b_out = (const float*)d_in[4];
    float* out = (float*)d_out;

    unsigned char* ws = (unsigned char*)d_ws;
    _Float16* Wt1 = (_Float16*)(ws);                          // 6.29 MB [3072][1024]
    _Float16* Wt2 = (_Float16*)(ws + 6291456);                // 2.10 MB [1024][1024]
    _Float16* Ah1 = (_Float16*)(ws + 8388608);                // 4.19 MB [2048][1024]
    unsigned short* proj = (unsigned short*)(ws + 16777216);  // 12.58 MB bf16 [2048][3072]
    _Float16* Oh = Ah1;   // reuse: Ah1 dead after gemm1

    // 1) fused prep: convert A to f16 + transpose both weights
    prep_kernel<<<3072, 256, 0, stream>>>(qkv, Ah1, w_in, Wt1, w_out, Wt2);

    // 2) proj = qkv @ w_in + b_in (1-pass f16, BK=64, bf16 out, q pre-scaled)
    gemm_f16_kernel<128, 96, 1, 0><<<512, 256, 0, stream>>>(
        Ah1, Ah1, Wt1, b_in, (void*)proj, S_LEN, 3 * E_DIM, E_DIM, 32);

    // 3) flash attention (r19: K-DMA double buffer, 2-barrier tiles) -> Oh f16
    attn_mfma_kernel<<<512, 512, 0, stream>>>(proj, Oh);

    // 4) out = attn @ w_out + b_out (1-pass f16, BK=64, fp32 out)
    gemm_f16_kernel<64, 64, 0, 0><<<512, 256, 0, stream>>>(
        Oh, Oh, Wt2, b_out, (void*)out, S_LEN, E_DIM, E_DIM, 16);
}